// Round 4
// baseline (232.950 us; speedup 1.0000x reference)
//
#include <hip/hip_runtime.h>
#include <hip/hip_bf16.h>

// Problem constants (reference: B=2, S=2048, D=1024, H=16, DEPTH=64)
constexpr int Bn = 2, Sn = 2048, Dn = 1024, Hn = 16, DEP = 64;
constexpr int NTOKn = Bn * Sn;  // 4096 rows for the token-dim GEMMs

typedef __bf16 bf16x8 __attribute__((ext_vector_type(8)));
typedef float f32x4 __attribute__((ext_vector_type(4)));

__device__ __forceinline__ unsigned short f2bf(float f) {
    union { __hip_bfloat16 h; unsigned short u; } cv;
    cv.h = __float2bfloat16(f);
    return cv.u;
}

// async global->LDS, 16B per lane. LDS dest must be wave-uniform base + lane*16.
__device__ __forceinline__ void gll16(const void* g, void* l) {
    __builtin_amdgcn_global_load_lds(
        (const __attribute__((address_space(1))) unsigned int*)g,
        (__attribute__((address_space(3))) unsigned int*)l, 16, 0, 0);
}

// ---------------- fused prep: x f32->bf16 convert + 4x weight transpose ----------------
// blocks [0,4096): x convert (1024 elems each). blocks [4096,5120): weight
// transpose-convert, 256 blocks per weight (16x16 of 64x64 tiles).
__global__ __launch_bounds__(256) void k_prep(const float* __restrict__ x,
                                              const float* __restrict__ w0,
                                              const float* __restrict__ w1,
                                              const float* __restrict__ w2,
                                              const float* __restrict__ w3,
                                              unsigned short* __restrict__ xb,
                                              unsigned short* __restrict__ t0,
                                              unsigned short* __restrict__ t1,
                                              unsigned short* __restrict__ t2,
                                              unsigned short* __restrict__ t3) {
    const int bid = blockIdx.x;
    const int t = threadIdx.x;
    if (bid < 4096) {
        const int idx = (bid * 256 + t) * 4;
        float4 v = *reinterpret_cast<const float4*>(x + idx);
        ushort4 o;
        o.x = f2bf(v.x); o.y = f2bf(v.y); o.z = f2bf(v.z); o.w = f2bf(v.w);
        *reinterpret_cast<ushort4*>(xb + idx) = o;
        return;
    }
    const int b2 = bid - 4096;
    const float* w; unsigned short* tp;
    switch (b2 >> 8) {
        case 0: w = w0; tp = t0; break;
        case 1: w = w1; tp = t1; break;
        case 2: w = w2; tp = t2; break;
        default: w = w3; tp = t3; break;
    }
    __shared__ unsigned short tile[64][65];
    const int k0 = ((b2 & 255) >> 4) * 64, n0 = (b2 & 15) * 64;
    const int c = t & 63, rb = t >> 6;
#pragma unroll
    for (int i = 0; i < 16; ++i) {
        int r = rb + i * 4;
        tile[r][c] = f2bf(w[(size_t)(k0 + r) * Dn + n0 + c]);
    }
    __syncthreads();
#pragma unroll
    for (int i = 0; i < 16; ++i) {
        int n = rb + i * 4;
        tp[(size_t)(n0 + n) * Dn + k0 + c] = tile[c][n];
    }
}

// ------------- transpose V: VT[(b*H+h)*64+d][s] = V[b*S+s][h*64+d] -------------
__global__ __launch_bounds__(256) void k_tr_v(const unsigned short* __restrict__ V,
                                              unsigned short* __restrict__ VT) {
    __shared__ unsigned short tile[64][65];
    const int s0 = blockIdx.x * 64;
    const int bh = blockIdx.y;
    const int b = bh >> 4, h = bh & 15;
    const int t = threadIdx.x;
    const int c = t & 63, rb = t >> 6;
#pragma unroll
    for (int i = 0; i < 16; ++i) {
        int r = rb + i * 4;
        tile[r][c] = V[(size_t)(b * Sn + s0 + r) * Dn + h * DEP + c];
    }
    __syncthreads();
#pragma unroll
    for (int i = 0; i < 16; ++i) {
        int d = rb + i * 4;
        VT[(size_t)(bh * DEP + d) * Sn + s0 + c] = tile[c][d];
    }
}

// =================== QKV GEMM, 8-phase-style 256x256 tile ===================
// (unchanged from R3 — counted vmcnt(4), T2 slot-swizzle, T5 setprio)
__global__ __launch_bounds__(512, 2) void k_qkv8(const unsigned short* __restrict__ A,
                                                 const unsigned short* __restrict__ Bt,
                                                 const float* __restrict__ bq,
                                                 const float* __restrict__ bk,
                                                 const float* __restrict__ bv,
                                                 unsigned short* __restrict__ qkv) {
    extern __shared__ char smem[];  // 131072 bytes
    constexpr int K = 1024, NT = K / 64;  // 16 K-steps

    const int t = threadIdx.x;
    const int w = t >> 6, l = t & 63;
    const int wm = w >> 2, wn = w & 3;
    const int m0 = blockIdx.x * 256;
    const int n0 = blockIdx.y * 256;
    const int z = n0 >> 10;

    const float* bias = (z == 0) ? bq : (z == 1 ? bk : bv);
    float biasv[4];
#pragma unroll
    for (int nf = 0; nf < 4; ++nf)
        biasv[nf] = bias[(n0 + wn * 64 + nf * 16 + (l & 15)) & 1023];

    int aoff[2], boff[2], ldsoff[2];
#pragma unroll
    for (int i = 0; i < 2; ++i) {
        const int idx = i * 512 + t;
        const int row = idx >> 2;
        const int s = ((idx & 3) - row - (row >> 2)) & 3;
        aoff[i] = (m0 + row) * K + s * 8;
        boff[i] = (n0 + row) * K + s * 8;
        ldsoff[i] = idx * 16;
    }

    f32x4 acc[8][4] = {};

#pragma unroll
    for (int kh = 0; kh < 2; ++kh) {
        if (kh == 0) {
#pragma unroll
            for (int i = 0; i < 2; ++i) gll16(A + aoff[i], smem + ldsoff[i]);
#pragma unroll
            for (int i = 0; i < 2; ++i) gll16(Bt + boff[i], smem + 65536 + ldsoff[i]);
        } else {
#pragma unroll
            for (int i = 0; i < 2; ++i) gll16(A + aoff[i] + 32, smem + 16384 + ldsoff[i]);
#pragma unroll
            for (int i = 0; i < 2; ++i) gll16(Bt + boff[i] + 32, smem + 65536 + 16384 + ldsoff[i]);
        }
    }

    for (int kb = 0; kb < NT; ++kb) {
        const int c = kb & 1;
        const int kn = (kb + 1 < NT) ? kb + 1 : NT - 1;
        const int cn = c ^ 1;
        const int Abase = c * 32768;
        const int Bbase = 65536 + c * 32768;
        const int AbaseN = cn * 32768;
        const int BbaseN = 65536 + cn * 32768;

        bf16x8 bf[4], af[4];

#pragma unroll
        for (int ph = 0; ph < 4; ++ph) {
            const int kk = ph >> 1;
            const int mb = (ph & 1) * 4;

            if ((ph & 1) == 0) {
                asm volatile("s_waitcnt vmcnt(4)" ::: "memory");
            }
            __builtin_amdgcn_s_barrier();
            __builtin_amdgcn_sched_barrier(0);

            if ((ph & 1) == 0) {
#pragma unroll
                for (int nf = 0; nf < 4; ++nf) {
                    const int row = wn * 64 + nf * 16 + (l & 15);
                    const int byte = Bbase + kk * 16384 + row * 64 +
                                     ((((l >> 4) + row + (row >> 2)) & 3) * 16);
                    bf[nf] = *reinterpret_cast<const bf16x8*>(smem + byte);
                }
            }
#pragma unroll
            for (int mfl = 0; mfl < 4; ++mfl) {
                const int row = wm * 128 + (mb + mfl) * 16 + (l & 15);
                const int byte = Abase + kk * 16384 + row * 64 +
                                 ((((l >> 4) + row + (row >> 2)) & 3) * 16);
                af[mfl] = *reinterpret_cast<const bf16x8*>(smem + byte);
            }

            {
                const int khs = ph >> 1;
                if ((ph & 1) == 0) {
#pragma unroll
                    for (int i = 0; i < 2; ++i)
                        gll16(A + aoff[i] + kn * 64 + khs * 32,
                              smem + AbaseN + khs * 16384 + ldsoff[i]);
                } else {
#pragma unroll
                    for (int i = 0; i < 2; ++i)
                        gll16(Bt + boff[i] + kn * 64 + khs * 32,
                              smem + BbaseN + khs * 16384 + ldsoff[i]);
                }
            }

            asm volatile("s_waitcnt lgkmcnt(0)" ::: "memory");
            __builtin_amdgcn_sched_barrier(0);
            __builtin_amdgcn_s_setprio(1);
#pragma unroll
            for (int mfl = 0; mfl < 4; ++mfl)
#pragma unroll
                for (int nf = 0; nf < 4; ++nf)
                    acc[mb + mfl][nf] = __builtin_amdgcn_mfma_f32_16x16x32_bf16(
                        af[mfl], bf[nf], acc[mb + mfl][nf], 0, 0, 0);
            __builtin_amdgcn_s_setprio(0);
        }
    }

    asm volatile("s_waitcnt vmcnt(0)" ::: "memory");

    unsigned short* outz = qkv + (size_t)z * NTOKn * Dn;
#pragma unroll
    for (int mf = 0; mf < 8; ++mf) {
        const int row = m0 + wm * 128 + mf * 16 + (l >> 4) * 4;
#pragma unroll
        for (int nf = 0; nf < 4; ++nf) {
            const int col = (n0 + wn * 64 + nf * 16 + (l & 15)) & 1023;
#pragma unroll
            for (int i = 0; i < 4; ++i)
                outz[(size_t)(row + i) * Dn + col] = f2bf(acc[mf][nf][i] + biasv[nf]);
        }
    }
}

// ---------------- bf16 GEMM (m97 structure) for the out-projection ----------------
__global__ __launch_bounds__(256) void k_gemm_op(const unsigned short* __restrict__ A,
                                                 const unsigned short* __restrict__ Bt,
                                                 const float* __restrict__ bias,
                                                 float* __restrict__ C,
                                                 int M, int N, int K) {
    __shared__ unsigned short As[128][32];
    __shared__ unsigned short Bs[128][32];
    const int t = threadIdx.x;
    const int w = t >> 6, l = t & 63;
    const int m0 = blockIdx.x * 128, n0 = blockIdx.y * 128;
    const int wr = (w >> 1) * 64, wc = (w & 1) * 64;

    const int lrow = t >> 2;
    const int lcol = (t & 3) * 8;
    const unsigned short* gA = A + (size_t)(m0 + lrow) * K + lcol;
    const unsigned short* gB = Bt + (size_t)(n0 + lrow) * K + lcol;
    unsigned short* lA = &As[0][0] + t * 8;
    unsigned short* lB = &Bs[0][0] + t * 8;

    f32x4 acc[4][4] = {};

    for (int k0 = 0; k0 < K; k0 += 32) {
        __syncthreads();
        gll16(gA + k0, lA);
        gll16(gA + (size_t)64 * K + k0, lA + 2048);
        gll16(gB + k0, lB);
        gll16(gB + (size_t)64 * K + k0, lB + 2048);
        __syncthreads();

        bf16x8 af[4], bfv[4];
#pragma unroll
        for (int i = 0; i < 4; ++i)
            af[i] = *reinterpret_cast<const bf16x8*>(&As[wr + i * 16 + (l & 15)][(l >> 4) * 8]);
#pragma unroll
        for (int i = 0; i < 4; ++i)
            bfv[i] = *reinterpret_cast<const bf16x8*>(&Bs[wc + i * 16 + (l & 15)][(l >> 4) * 8]);
#pragma unroll
        for (int mi = 0; mi < 4; ++mi)
#pragma unroll
            for (int ni = 0; ni < 4; ++ni)
                acc[mi][ni] =
                    __builtin_amdgcn_mfma_f32_16x16x32_bf16(af[mi], bfv[ni], acc[mi][ni], 0, 0, 0);
    }

#pragma unroll
    for (int mi = 0; mi < 4; ++mi) {
        const int row = m0 + wr + mi * 16 + (l >> 4) * 4;
#pragma unroll
        for (int ni = 0; ni < 4; ++ni) {
            const int col = n0 + wc + ni * 16 + (l & 15);
            const float bv = bias[col];
#pragma unroll
            for (int i = 0; i < 4; ++i)
                C[(size_t)(row + i) * N + col] = acc[mi][ni][i] + bv;
        }
    }
}

// ---------------- fused attention: attn = relu(QK^T*scale), ctx = attn @ V ----------------
// XCD-aware remap: all 16 q-blocks of a head land on one XCD (4 heads/XCD,
// K/V working set 2 MB <= 4 MB L2). attn stores are non-temporal (streaming,
// never re-read) so they don't evict K/V from L2. Store-overlap schedule with
// counted vmcnt(63) unchanged from R2/R3.
__global__ __launch_bounds__(256, 2) void k_attn(const unsigned short* __restrict__ Qb,
                                                 const unsigned short* __restrict__ Kb,
                                                 const unsigned short* __restrict__ VTb,
                                                 float* __restrict__ attn,
                                                 unsigned short* __restrict__ ctx) {
    __shared__ unsigned short Ks[128 * 64];
    __shared__ unsigned short Vs[64 * 128];
    __shared__ unsigned short Ps[4][32][136];

    const int t = threadIdx.x;
    const int w = t >> 6, l = t & 63;

    // XCD-aware bijective remap (dispatch round-robins linear%8 across XCDs)
    const int lin = blockIdx.x + 16 * blockIdx.y;
    const int xcd = lin & 7, idx = lin >> 3;
    const int bh = xcd * 4 + (idx >> 4);
    const int q0 = (idx & 15) * 128;
    const int b = bh >> 4, h = bh & 15;
    const float scale = 0.125f;  // 1/sqrt(64)

    bf16x8 qf[2][2];
#pragma unroll
    for (int mi = 0; mi < 2; ++mi)
#pragma unroll
        for (int kk = 0; kk < 2; ++kk)
            qf[mi][kk] = *reinterpret_cast<const bf16x8*>(
                Qb + (size_t)(b * Sn + q0 + w * 32 + mi * 16 + (l & 15)) * Dn + h * DEP +
                kk * 32 + (l >> 4) * 8);

    const int krow = t >> 3;
    const int kcolswz = ((t & 7) * 8) ^ ((krow & 7) << 3);
    const int vrow = t >> 4;
    const int vcolswz = ((t & 15) * 8) ^ ((vrow & 7) << 3);
    unsigned short* lK = Ks + t * 8;
    unsigned short* lV = Vs + t * 8;

    f32x4 ctxa[2][4] = {};
    f32x4 sa[2][8];

    float* const abase = attn + (size_t)bh * Sn * Sn + (size_t)(q0 + w * 32) * Sn;

    auto STAGE = [&](int kb) {
#pragma unroll
        for (int is = 0; is < 4; ++is) {
            gll16(Kb + (size_t)(b * Sn + kb * 128 + is * 32 + krow) * Dn + h * DEP + kcolswz,
                  lK + is * 2048);
            gll16(VTb + (size_t)(bh * DEP + is * 16 + vrow) * Sn + kb * 128 + vcolswz,
                  lV + is * 2048);
        }
    };

    auto QKT = [&]() {
#pragma unroll
        for (int mi = 0; mi < 2; ++mi)
#pragma unroll
            for (int nj = 0; nj < 8; ++nj)
                sa[mi][nj] = (f32x4){0.f, 0.f, 0.f, 0.f};
#pragma unroll
        for (int nj = 0; nj < 8; ++nj) {
            const int kr = nj * 16 + (l & 15);
#pragma unroll
            for (int kk = 0; kk < 2; ++kk) {
                const int kidx = (kr * 64 + kk * 32 + (l >> 4) * 8) ^ ((kr & 7) << 3);
                const bf16x8 bfr = *reinterpret_cast<const bf16x8*>(Ks + kidx);
                sa[0][nj] = __builtin_amdgcn_mfma_f32_16x16x32_bf16(qf[0][kk], bfr, sa[0][nj], 0, 0, 0);
                sa[1][nj] = __builtin_amdgcn_mfma_f32_16x16x32_bf16(qf[1][kk], bfr, sa[1][nj], 0, 0, 0);
            }
        }
#pragma unroll
        for (int mi = 0; mi < 2; ++mi) {
#pragma unroll
            for (int nj = 0; nj < 8; ++nj) {
                f32x4 v = sa[mi][nj];
#pragma unroll
                for (int i = 0; i < 4; ++i) {
                    float p = v[i] * scale;
                    v[i] = p > 0.f ? p : 0.f;
                }
                sa[mi][nj] = v;
                const int kc = nj * 16 + (l & 15);
#pragma unroll
                for (int i = 0; i < 4; ++i)
                    Ps[w][mi * 16 + (l >> 4) * 4 + i][kc] = f2bf(v[i]);
            }
        }
    };

    auto PV = [&]() {
        bf16x8 pf[2][4];
#pragma unroll
        for (int mi = 0; mi < 2; ++mi)
#pragma unroll
            for (int kk = 0; kk < 4; ++kk)
                pf[mi][kk] = *reinterpret_cast<const bf16x8*>(
                    &Ps[w][mi * 16 + (l & 15)][kk * 32 + (l >> 4) * 8]);
#pragma unroll
        for (int nd = 0; nd < 4; ++nd) {
            const int vr = nd * 16 + (l & 15);
#pragma unroll
            for (int kk = 0; kk < 4; ++kk) {
                const int vidx = (vr * 128 + kk * 32 + (l >> 4) * 8) ^ ((vr & 7) << 3);
                const bf16x8 vfr = *reinterpret_cast<const bf16x8*>(Vs + vidx);
                ctxa[0][nd] = __builtin_amdgcn_mfma_f32_16x16x32_bf16(pf[0][kk], vfr, ctxa[0][nd], 0, 0, 0);
                ctxa[1][nd] = __builtin_amdgcn_mfma_f32_16x16x32_bf16(pf[1][kk], vfr, ctxa[1][nd], 0, 0, 0);
            }
        }
    };

    // streaming (non-temporal) attn stores; (row, col) order so each 4-row
    // group writes 8 consecutive 64B chunks per row before moving on.
    auto STORE_SA = [&](int kb) {
        float* arow = abase + kb * 128;
#pragma unroll
        for (int mi = 0; mi < 2; ++mi)
#pragma unroll
            for (int i = 0; i < 4; ++i) {
                float* r = arow + (size_t)(mi * 16 + (l >> 4) * 4 + i) * Sn + (l & 15);
#pragma unroll
                for (int nj = 0; nj < 8; ++nj)
                    __builtin_nontemporal_store(sa[mi][nj][i], r + nj * 16);
            }
    };

    STAGE(0);
    asm volatile("s_waitcnt vmcnt(0)" ::: "memory");
    __builtin_amdgcn_s_barrier();
    __builtin_amdgcn_sched_barrier(0);
    QKT();
    PV();

    for (int kb = 1; kb < Sn / 128; ++kb) {
        asm volatile("s_waitcnt lgkmcnt(0)" ::: "memory");
        __builtin_amdgcn_s_barrier();
        __builtin_amdgcn_sched_barrier(0);
        STAGE(kb);
        asm volatile("" ::: "memory");
        STORE_SA(kb - 1);
        asm volatile("s_waitcnt vmcnt(63)" ::: "memory");
        __builtin_amdgcn_s_barrier();
        __builtin_amdgcn_sched_barrier(0);
        QKT();
        PV();
    }
    STORE_SA(Sn / 128 - 1);

#pragma unroll
    for (int mi = 0; mi < 2; ++mi) {
#pragma unroll
        for (int nd = 0; nd < 4; ++nd) {
            const int dc = nd * 16 + (l & 15);
#pragma unroll
            for (int i = 0; i < 4; ++i) {
                const int qr = q0 + w * 32 + mi * 16 + (l >> 4) * 4 + i;
                ctx[(size_t)(b * Sn + qr) * Dn + h * DEP + dc] = f2bf(ctxa[mi][nd][i]);
            }
        }
    }
}

extern "C" void kernel_launch(void* const* d_in, const int* in_sizes, int n_in,
                              void* d_out, int out_size, void* d_ws, size_t ws_size,
                              hipStream_t stream) {
    (void)in_sizes; (void)n_in; (void)out_size; (void)ws_size;
    const float* x  = (const float*)d_in[0];
    const float* wq = (const float*)d_in[1];
    const float* bq = (const float*)d_in[2];
    const float* wk = (const float*)d_in[3];
    const float* bk = (const float*)d_in[4];
    const float* wv = (const float*)d_in[5];
    const float* bv = (const float*)d_in[6];
    const float* wo = (const float*)d_in[7];
    const float* bo = (const float*)d_in[8];

    float* out  = (float*)d_out;
    float* attn = out + (size_t)Bn * Sn * Dn;  // outputs concatenated: (out, attn)

    char* ws = (char*)d_ws;
    unsigned short* xb = (unsigned short*)ws;  ws += (size_t)NTOKn * Dn * 2;       // 8 MB
    unsigned short* wT = (unsigned short*)ws;  ws += (size_t)4 * Dn * Dn * 2;      // 8 MB [q,k,v,o]
    unsigned short* qkv = (unsigned short*)ws; ws += (size_t)3 * NTOKn * Dn * 2;   // 24 MB
    unsigned short* vT = (unsigned short*)ws;  ws += (size_t)NTOKn * Dn * 2;       // 8 MB
    unsigned short* ctx = (unsigned short*)ws;                                     // 8 MB

    const size_t DD = (size_t)Dn * Dn;

    static bool attr_set = false;
    if (!attr_set) {
        hipFuncSetAttribute(reinterpret_cast<const void*>(k_qkv8),
                            hipFuncAttributeMaxDynamicSharedMemorySize, 131072);
        attr_set = true;
    }

    k_prep<<<dim3(5120), 256, 0, stream>>>(x, wq, wk, wv, wo, xb,
                                           wT, wT + DD, wT + 2 * DD, wT + 3 * DD);
    k_qkv8<<<dim3(16, 12), 512, 131072, stream>>>(xb, wT, bq, bk, bv, qkv);
    k_tr_v<<<dim3(32, 32), 256, 0, stream>>>(qkv + (size_t)2 * NTOKn * Dn, vT);
    k_attn<<<dim3(16, 32), 256, 0, stream>>>(qkv, qkv + (size_t)NTOKn * Dn, vT, attn, ctx);
    k_gemm_op<<<dim3(32, 8), 256, 0, stream>>>(ctx, wT + 3 * DD, bo, out, NTOKn, Dn, Dn);
}

// Round 5
// 216.076 us; speedup vs baseline: 1.0781x; 1.0781x over previous
//
#include <hip/hip_runtime.h>
#include <hip/hip_bf16.h>

// Problem constants (reference: B=2, S=2048, D=1024, H=16, DEPTH=64)
constexpr int Bn = 2, Sn = 2048, Dn = 1024, Hn = 16, DEP = 64;
constexpr int NTOKn = Bn * Sn;  // 4096 rows for the token-dim GEMMs

typedef __bf16 bf16x8 __attribute__((ext_vector_type(8)));
typedef float f32x4 __attribute__((ext_vector_type(4)));

__device__ __forceinline__ unsigned short f2bf(float f) {
    union { __hip_bfloat16 h; unsigned short u; } cv;
    cv.h = __float2bfloat16(f);
    return cv.u;
}

// async global->LDS, 16B per lane. LDS dest must be wave-uniform base + lane*16.
__device__ __forceinline__ void gll16(const void* g, void* l) {
    __builtin_amdgcn_global_load_lds(
        (const __attribute__((address_space(1))) unsigned int*)g,
        (__attribute__((address_space(3))) unsigned int*)l, 16, 0, 0);
}

// ---------------- fused prep: x f32->bf16 convert + 4x weight transpose ----------------
__global__ __launch_bounds__(256) void k_prep(const float* __restrict__ x,
                                              const float* __restrict__ w0,
                                              const float* __restrict__ w1,
                                              const float* __restrict__ w2,
                                              const float* __restrict__ w3,
                                              unsigned short* __restrict__ xb,
                                              unsigned short* __restrict__ t0,
                                              unsigned short* __restrict__ t1,
                                              unsigned short* __restrict__ t2,
                                              unsigned short* __restrict__ t3) {
    const int bid = blockIdx.x;
    const int t = threadIdx.x;
    if (bid < 4096) {
        const int idx = (bid * 256 + t) * 4;
        float4 v = *reinterpret_cast<const float4*>(x + idx);
        ushort4 o;
        o.x = f2bf(v.x); o.y = f2bf(v.y); o.z = f2bf(v.z); o.w = f2bf(v.w);
        *reinterpret_cast<ushort4*>(xb + idx) = o;
        return;
    }
    const int b2 = bid - 4096;
    const float* w; unsigned short* tp;
    switch (b2 >> 8) {
        case 0: w = w0; tp = t0; break;
        case 1: w = w1; tp = t1; break;
        case 2: w = w2; tp = t2; break;
        default: w = w3; tp = t3; break;
    }
    __shared__ unsigned short tile[64][65];
    const int k0 = ((b2 & 255) >> 4) * 64, n0 = (b2 & 15) * 64;
    const int c = t & 63, rb = t >> 6;
#pragma unroll
    for (int i = 0; i < 16; ++i) {
        int r = rb + i * 4;
        tile[r][c] = f2bf(w[(size_t)(k0 + r) * Dn + n0 + c]);
    }
    __syncthreads();
#pragma unroll
    for (int i = 0; i < 16; ++i) {
        int n = rb + i * 4;
        tp[(size_t)(n0 + n) * Dn + k0 + c] = tile[c][n];
    }
}

// ------------- transpose V: VT[(b*H+h)*64+d][s] = V[b*S+s][h*64+d] -------------
__global__ __launch_bounds__(256) void k_tr_v(const unsigned short* __restrict__ V,
                                              unsigned short* __restrict__ VT) {
    __shared__ unsigned short tile[64][65];
    const int s0 = blockIdx.x * 64;
    const int bh = blockIdx.y;
    const int b = bh >> 4, h = bh & 15;
    const int t = threadIdx.x;
    const int c = t & 63, rb = t >> 6;
#pragma unroll
    for (int i = 0; i < 16; ++i) {
        int r = rb + i * 4;
        tile[r][c] = V[(size_t)(b * Sn + s0 + r) * Dn + h * DEP + c];
    }
    __syncthreads();
#pragma unroll
    for (int i = 0; i < 16; ++i) {
        int d = rb + i * 4;
        VT[(size_t)(bh * DEP + d) * Sn + s0 + c] = tile[c][d];
    }
}

// =================== QKV GEMM, 8-phase-style 256x256 tile ===================
// (counted vmcnt(4), T2 slot-swizzle, T5 setprio)
__global__ __launch_bounds__(512, 2) void k_qkv8(const unsigned short* __restrict__ A,
                                                 const unsigned short* __restrict__ Bt,
                                                 const float* __restrict__ bq,
                                                 const float* __restrict__ bk,
                                                 const float* __restrict__ bv,
                                                 unsigned short* __restrict__ qkv) {
    extern __shared__ char smem[];  // 131072 bytes
    constexpr int K = 1024, NT = K / 64;  // 16 K-steps

    const int t = threadIdx.x;
    const int w = t >> 6, l = t & 63;
    const int wm = w >> 2, wn = w & 3;
    const int m0 = blockIdx.x * 256;
    const int n0 = blockIdx.y * 256;
    const int z = n0 >> 10;

    const float* bias = (z == 0) ? bq : (z == 1 ? bk : bv);
    float biasv[4];
#pragma unroll
    for (int nf = 0; nf < 4; ++nf)
        biasv[nf] = bias[(n0 + wn * 64 + nf * 16 + (l & 15)) & 1023];

    int aoff[2], boff[2], ldsoff[2];
#pragma unroll
    for (int i = 0; i < 2; ++i) {
        const int idx = i * 512 + t;
        const int row = idx >> 2;
        const int s = ((idx & 3) - row - (row >> 2)) & 3;
        aoff[i] = (m0 + row) * K + s * 8;
        boff[i] = (n0 + row) * K + s * 8;
        ldsoff[i] = idx * 16;
    }

    f32x4 acc[8][4] = {};

#pragma unroll
    for (int kh = 0; kh < 2; ++kh) {
        if (kh == 0) {
#pragma unroll
            for (int i = 0; i < 2; ++i) gll16(A + aoff[i], smem + ldsoff[i]);
#pragma unroll
            for (int i = 0; i < 2; ++i) gll16(Bt + boff[i], smem + 65536 + ldsoff[i]);
        } else {
#pragma unroll
            for (int i = 0; i < 2; ++i) gll16(A + aoff[i] + 32, smem + 16384 + ldsoff[i]);
#pragma unroll
            for (int i = 0; i < 2; ++i) gll16(Bt + boff[i] + 32, smem + 65536 + 16384 + ldsoff[i]);
        }
    }

    for (int kb = 0; kb < NT; ++kb) {
        const int c = kb & 1;
        const int kn = (kb + 1 < NT) ? kb + 1 : NT - 1;
        const int cn = c ^ 1;
        const int Abase = c * 32768;
        const int Bbase = 65536 + c * 32768;
        const int AbaseN = cn * 32768;
        const int BbaseN = 65536 + cn * 32768;

        bf16x8 bf[4], af[4];

#pragma unroll
        for (int ph = 0; ph < 4; ++ph) {
            const int kk = ph >> 1;
            const int mb = (ph & 1) * 4;

            if ((ph & 1) == 0) {
                asm volatile("s_waitcnt vmcnt(4)" ::: "memory");
            }
            __builtin_amdgcn_s_barrier();
            __builtin_amdgcn_sched_barrier(0);

            if ((ph & 1) == 0) {
#pragma unroll
                for (int nf = 0; nf < 4; ++nf) {
                    const int row = wn * 64 + nf * 16 + (l & 15);
                    const int byte = Bbase + kk * 16384 + row * 64 +
                                     ((((l >> 4) + row + (row >> 2)) & 3) * 16);
                    bf[nf] = *reinterpret_cast<const bf16x8*>(smem + byte);
                }
            }
#pragma unroll
            for (int mfl = 0; mfl < 4; ++mfl) {
                const int row = wm * 128 + (mb + mfl) * 16 + (l & 15);
                const int byte = Abase + kk * 16384 + row * 64 +
                                 ((((l >> 4) + row + (row >> 2)) & 3) * 16);
                af[mfl] = *reinterpret_cast<const bf16x8*>(smem + byte);
            }

            {
                const int khs = ph >> 1;
                if ((ph & 1) == 0) {
#pragma unroll
                    for (int i = 0; i < 2; ++i)
                        gll16(A + aoff[i] + kn * 64 + khs * 32,
                              smem + AbaseN + khs * 16384 + ldsoff[i]);
                } else {
#pragma unroll
                    for (int i = 0; i < 2; ++i)
                        gll16(Bt + boff[i] + kn * 64 + khs * 32,
                              smem + BbaseN + khs * 16384 + ldsoff[i]);
                }
            }

            asm volatile("s_waitcnt lgkmcnt(0)" ::: "memory");
            __builtin_amdgcn_sched_barrier(0);
            __builtin_amdgcn_s_setprio(1);
#pragma unroll
            for (int mfl = 0; mfl < 4; ++mfl)
#pragma unroll
                for (int nf = 0; nf < 4; ++nf)
                    acc[mb + mfl][nf] = __builtin_amdgcn_mfma_f32_16x16x32_bf16(
                        af[mfl], bf[nf], acc[mb + mfl][nf], 0, 0, 0);
            __builtin_amdgcn_s_setprio(0);
        }
    }

    asm volatile("s_waitcnt vmcnt(0)" ::: "memory");

    unsigned short* outz = qkv + (size_t)z * NTOKn * Dn;
#pragma unroll
    for (int mf = 0; mf < 8; ++mf) {
        const int row = m0 + wm * 128 + mf * 16 + (l >> 4) * 4;
#pragma unroll
        for (int nf = 0; nf < 4; ++nf) {
            const int col = (n0 + wn * 64 + nf * 16 + (l & 15)) & 1023;
#pragma unroll
            for (int i = 0; i < 4; ++i)
                outz[(size_t)(row + i) * Dn + col] = f2bf(acc[mf][nf][i] + biasv[nf]);
        }
    }
}

// ---------------- bf16 GEMM (m97 structure) for the out-projection ----------------
__global__ __launch_bounds__(256) void k_gemm_op(const unsigned short* __restrict__ A,
                                                 const unsigned short* __restrict__ Bt,
                                                 const float* __restrict__ bias,
                                                 float* __restrict__ C,
                                                 int M, int N, int K) {
    __shared__ unsigned short As[128][32];
    __shared__ unsigned short Bs[128][32];
    const int t = threadIdx.x;
    const int w = t >> 6, l = t & 63;
    const int m0 = blockIdx.x * 128, n0 = blockIdx.y * 128;
    const int wr = (w >> 1) * 64, wc = (w & 1) * 64;

    const int lrow = t >> 2;
    const int lcol = (t & 3) * 8;
    const unsigned short* gA = A + (size_t)(m0 + lrow) * K + lcol;
    const unsigned short* gB = Bt + (size_t)(n0 + lrow) * K + lcol;
    unsigned short* lA = &As[0][0] + t * 8;
    unsigned short* lB = &Bs[0][0] + t * 8;

    f32x4 acc[4][4] = {};

    for (int k0 = 0; k0 < K; k0 += 32) {
        __syncthreads();
        gll16(gA + k0, lA);
        gll16(gA + (size_t)64 * K + k0, lA + 2048);
        gll16(gB + k0, lB);
        gll16(gB + (size_t)64 * K + k0, lB + 2048);
        __syncthreads();

        bf16x8 af[4], bfv[4];
#pragma unroll
        for (int i = 0; i < 4; ++i)
            af[i] = *reinterpret_cast<const bf16x8*>(&As[wr + i * 16 + (l & 15)][(l >> 4) * 8]);
#pragma unroll
        for (int i = 0; i < 4; ++i)
            bfv[i] = *reinterpret_cast<const bf16x8*>(&Bs[wc + i * 16 + (l & 15)][(l >> 4) * 8]);
#pragma unroll
        for (int mi = 0; mi < 4; ++mi)
#pragma unroll
            for (int ni = 0; ni < 4; ++ni)
                acc[mi][ni] =
                    __builtin_amdgcn_mfma_f32_16x16x32_bf16(af[mi], bfv[ni], acc[mi][ni], 0, 0, 0);
    }

#pragma unroll
    for (int mi = 0; mi < 4; ++mi) {
        const int row = m0 + wr + mi * 16 + (l >> 4) * 4;
#pragma unroll
        for (int ni = 0; ni < 4; ++ni) {
            const int col = n0 + wc + ni * 16 + (l & 15);
            const float bv = bias[col];
#pragma unroll
            for (int i = 0; i < 4; ++i)
                C[(size_t)(row + i) * N + col] = acc[mi][ni][i] + bv;
        }
    }
}

// ---------------- fused attention: attn = relu(QK^T*scale), ctx = attn @ V ----------------
// XCD-aware remap kept (each XCD owns 4 heads, K/V L2-resident); attn stores
// back to PLAIN cached stores (R4's nt-stores regressed — suspected write-BW
// loss from no-allocate path). Store-overlap schedule with counted vmcnt(63).
__global__ __launch_bounds__(256, 2) void k_attn(const unsigned short* __restrict__ Qb,
                                                 const unsigned short* __restrict__ Kb,
                                                 const unsigned short* __restrict__ VTb,
                                                 float* __restrict__ attn,
                                                 unsigned short* __restrict__ ctx) {
    __shared__ unsigned short Ks[128 * 64];
    __shared__ unsigned short Vs[64 * 128];
    __shared__ unsigned short Ps[4][32][136];

    const int t = threadIdx.x;
    const int w = t >> 6, l = t & 63;

    // XCD-aware bijective remap (dispatch round-robins linear%8 across XCDs)
    const int lin = blockIdx.x + 16 * blockIdx.y;
    const int xcd = lin & 7, idx = lin >> 3;
    const int bh = xcd * 4 + (idx >> 4);
    const int q0 = (idx & 15) * 128;
    const int b = bh >> 4, h = bh & 15;
    const float scale = 0.125f;  // 1/sqrt(64)

    bf16x8 qf[2][2];
#pragma unroll
    for (int mi = 0; mi < 2; ++mi)
#pragma unroll
        for (int kk = 0; kk < 2; ++kk)
            qf[mi][kk] = *reinterpret_cast<const bf16x8*>(
                Qb + (size_t)(b * Sn + q0 + w * 32 + mi * 16 + (l & 15)) * Dn + h * DEP +
                kk * 32 + (l >> 4) * 8);

    const int krow = t >> 3;
    const int kcolswz = ((t & 7) * 8) ^ ((krow & 7) << 3);
    const int vrow = t >> 4;
    const int vcolswz = ((t & 15) * 8) ^ ((vrow & 7) << 3);
    unsigned short* lK = Ks + t * 8;
    unsigned short* lV = Vs + t * 8;

    f32x4 ctxa[2][4] = {};
    f32x4 sa[2][8];

    float* const abase = attn + (size_t)bh * Sn * Sn + (size_t)(q0 + w * 32) * Sn;

    auto STAGE = [&](int kb) {
#pragma unroll
        for (int is = 0; is < 4; ++is) {
            gll16(Kb + (size_t)(b * Sn + kb * 128 + is * 32 + krow) * Dn + h * DEP + kcolswz,
                  lK + is * 2048);
            gll16(VTb + (size_t)(bh * DEP + is * 16 + vrow) * Sn + kb * 128 + vcolswz,
                  lV + is * 2048);
        }
    };

    auto QKT = [&]() {
#pragma unroll
        for (int mi = 0; mi < 2; ++mi)
#pragma unroll
            for (int nj = 0; nj < 8; ++nj)
                sa[mi][nj] = (f32x4){0.f, 0.f, 0.f, 0.f};
#pragma unroll
        for (int nj = 0; nj < 8; ++nj) {
            const int kr = nj * 16 + (l & 15);
#pragma unroll
            for (int kk = 0; kk < 2; ++kk) {
                const int kidx = (kr * 64 + kk * 32 + (l >> 4) * 8) ^ ((kr & 7) << 3);
                const bf16x8 bfr = *reinterpret_cast<const bf16x8*>(Ks + kidx);
                sa[0][nj] = __builtin_amdgcn_mfma_f32_16x16x32_bf16(qf[0][kk], bfr, sa[0][nj], 0, 0, 0);
                sa[1][nj] = __builtin_amdgcn_mfma_f32_16x16x32_bf16(qf[1][kk], bfr, sa[1][nj], 0, 0, 0);
            }
        }
#pragma unroll
        for (int mi = 0; mi < 2; ++mi) {
#pragma unroll
            for (int nj = 0; nj < 8; ++nj) {
                f32x4 v = sa[mi][nj];
#pragma unroll
                for (int i = 0; i < 4; ++i) {
                    float p = v[i] * scale;
                    v[i] = p > 0.f ? p : 0.f;
                }
                sa[mi][nj] = v;
                const int kc = nj * 16 + (l & 15);
#pragma unroll
                for (int i = 0; i < 4; ++i)
                    Ps[w][mi * 16 + (l >> 4) * 4 + i][kc] = f2bf(v[i]);
            }
        }
    };

    auto PV = [&]() {
        bf16x8 pf[2][4];
#pragma unroll
        for (int mi = 0; mi < 2; ++mi)
#pragma unroll
            for (int kk = 0; kk < 4; ++kk)
                pf[mi][kk] = *reinterpret_cast<const bf16x8*>(
                    &Ps[w][mi * 16 + (l & 15)][kk * 32 + (l >> 4) * 8]);
#pragma unroll
        for (int nd = 0; nd < 4; ++nd) {
            const int vr = nd * 16 + (l & 15);
#pragma unroll
            for (int kk = 0; kk < 4; ++kk) {
                const int vidx = (vr * 128 + kk * 32 + (l >> 4) * 8) ^ ((vr & 7) << 3);
                const bf16x8 vfr = *reinterpret_cast<const bf16x8*>(Vs + vidx);
                ctxa[0][nd] = __builtin_amdgcn_mfma_f32_16x16x32_bf16(pf[0][kk], vfr, ctxa[0][nd], 0, 0, 0);
                ctxa[1][nd] = __builtin_amdgcn_mfma_f32_16x16x32_bf16(pf[1][kk], vfr, ctxa[1][nd], 0, 0, 0);
            }
        }
    };

    auto STORE_SA = [&](int kb) {  // plain cached stores (R3 version)
        float* arow = abase + kb * 128;
#pragma unroll
        for (int mi = 0; mi < 2; ++mi)
#pragma unroll
            for (int nj = 0; nj < 8; ++nj) {
                const int kc = nj * 16 + (l & 15);
#pragma unroll
                for (int i = 0; i < 4; ++i)
                    arow[(size_t)(mi * 16 + (l >> 4) * 4 + i) * Sn + kc] = sa[mi][nj][i];
            }
    };

    STAGE(0);
    asm volatile("s_waitcnt vmcnt(0)" ::: "memory");
    __builtin_amdgcn_s_barrier();
    __builtin_amdgcn_sched_barrier(0);
    QKT();
    PV();

    for (int kb = 1; kb < Sn / 128; ++kb) {
        asm volatile("s_waitcnt lgkmcnt(0)" ::: "memory");
        __builtin_amdgcn_s_barrier();
        __builtin_amdgcn_sched_barrier(0);
        STAGE(kb);
        asm volatile("" ::: "memory");
        STORE_SA(kb - 1);
        asm volatile("s_waitcnt vmcnt(63)" ::: "memory");
        __builtin_amdgcn_s_barrier();
        __builtin_amdgcn_sched_barrier(0);
        QKT();
        PV();
    }
    STORE_SA(Sn / 128 - 1);

#pragma unroll
    for (int mi = 0; mi < 2; ++mi) {
#pragma unroll
        for (int nd = 0; nd < 4; ++nd) {
            const int dc = nd * 16 + (l & 15);
#pragma unroll
            for (int i = 0; i < 4; ++i) {
                const int qr = q0 + w * 32 + mi * 16 + (l >> 4) * 4 + i;
                ctx[(size_t)(b * Sn + qr) * Dn + h * DEP + dc] = f2bf(ctxa[mi][nd][i]);
            }
        }
    }
}

extern "C" void kernel_launch(void* const* d_in, const int* in_sizes, int n_in,
                              void* d_out, int out_size, void* d_ws, size_t ws_size,
                              hipStream_t stream) {
    (void)in_sizes; (void)n_in; (void)out_size; (void)ws_size;
    const float* x  = (const float*)d_in[0];
    const float* wq = (const float*)d_in[1];
    const float* bq = (const float*)d_in[2];
    const float* wk = (const float*)d_in[3];
    const float* bk = (const float*)d_in[4];
    const float* wv = (const float*)d_in[5];
    const float* bv = (const float*)d_in[6];
    const float* wo = (const float*)d_in[7];
    const float* bo = (const float*)d_in[8];

    float* out  = (float*)d_out;
    float* attn = out + (size_t)Bn * Sn * Dn;  // outputs concatenated: (out, attn)

    char* ws = (char*)d_ws;
    unsigned short* xb = (unsigned short*)ws;  ws += (size_t)NTOKn * Dn * 2;       // 8 MB
    unsigned short* wT = (unsigned short*)ws;  ws += (size_t)4 * Dn * Dn * 2;      // 8 MB [q,k,v,o]
    unsigned short* qkv = (unsigned short*)ws; ws += (size_t)3 * NTOKn * Dn * 2;   // 24 MB
    unsigned short* vT = (unsigned short*)ws;  ws += (size_t)NTOKn * Dn * 2;       // 8 MB
    unsigned short* ctx = (unsigned short*)ws;                                     // 8 MB

    const size_t DD = (size_t)Dn * Dn;

    static bool attr_set = false;
    if (!attr_set) {
        hipFuncSetAttribute(reinterpret_cast<const void*>(k_qkv8),
                            hipFuncAttributeMaxDynamicSharedMemorySize, 131072);
        attr_set = true;
    }

    k_prep<<<dim3(5120), 256, 0, stream>>>(x, wq, wk, wv, wo, xb,
                                           wT, wT + DD, wT + 2 * DD, wT + 3 * DD);
    k_qkv8<<<dim3(16, 12), 512, 131072, stream>>>(xb, wT, bq, bk, bv, qkv);
    k_tr_v<<<dim3(32, 32), 256, 0, stream>>>(qkv + (size_t)2 * NTOKn * Dn, vT);
    k_attn<<<dim3(16, 32), 256, 0, stream>>>(qkv, qkv + (size_t)NTOKn * Dn, vT, attn, ctx);
    k_gemm_op<<<dim3(32, 8), 256, 0, stream>>>(ctx, wT + 3 * DD, bo, out, NTOKn, Dn, Dn);
}

// Round 6
// 215.377 us; speedup vs baseline: 1.0816x; 1.0032x over previous
//
#include <hip/hip_runtime.h>
#include <hip/hip_bf16.h>

// Problem constants (reference: B=2, S=2048, D=1024, H=16, DEPTH=64)
constexpr int Bn = 2, Sn = 2048, Dn = 1024, Hn = 16, DEP = 64;
constexpr int NTOKn = Bn * Sn;  // 4096 rows for the token-dim GEMMs

typedef __bf16 bf16x8 __attribute__((ext_vector_type(8)));
typedef float f32x4 __attribute__((ext_vector_type(4)));

__device__ __forceinline__ unsigned short f2bf(float f) {
    union { __hip_bfloat16 h; unsigned short u; } cv;
    cv.h = __float2bfloat16(f);
    return cv.u;
}

// async global->LDS, 16B per lane. LDS dest must be wave-uniform base + lane*16.
__device__ __forceinline__ void gll16(const void* g, void* l) {
    __builtin_amdgcn_global_load_lds(
        (const __attribute__((address_space(1))) unsigned int*)g,
        (__attribute__((address_space(3))) unsigned int*)l, 16, 0, 0);
}

// ---------------- fused prep: x f32->bf16 convert + 4x weight transpose ----------------
__global__ __launch_bounds__(256) void k_prep(const float* __restrict__ x,
                                              const float* __restrict__ w0,
                                              const float* __restrict__ w1,
                                              const float* __restrict__ w2,
                                              const float* __restrict__ w3,
                                              unsigned short* __restrict__ xb,
                                              unsigned short* __restrict__ t0,
                                              unsigned short* __restrict__ t1,
                                              unsigned short* __restrict__ t2,
                                              unsigned short* __restrict__ t3) {
    const int bid = blockIdx.x;
    const int t = threadIdx.x;
    if (bid < 4096) {
        const int idx = (bid * 256 + t) * 4;
        float4 v = *reinterpret_cast<const float4*>(x + idx);
        ushort4 o;
        o.x = f2bf(v.x); o.y = f2bf(v.y); o.z = f2bf(v.z); o.w = f2bf(v.w);
        *reinterpret_cast<ushort4*>(xb + idx) = o;
        return;
    }
    const int b2 = bid - 4096;
    const float* w; unsigned short* tp;
    switch (b2 >> 8) {
        case 0: w = w0; tp = t0; break;
        case 1: w = w1; tp = t1; break;
        case 2: w = w2; tp = t2; break;
        default: w = w3; tp = t3; break;
    }
    __shared__ unsigned short tile[64][65];
    const int k0 = ((b2 & 255) >> 4) * 64, n0 = (b2 & 15) * 64;
    const int c = t & 63, rb = t >> 6;
#pragma unroll
    for (int i = 0; i < 16; ++i) {
        int r = rb + i * 4;
        tile[r][c] = f2bf(w[(size_t)(k0 + r) * Dn + n0 + c]);
    }
    __syncthreads();
#pragma unroll
    for (int i = 0; i < 16; ++i) {
        int n = rb + i * 4;
        tp[(size_t)(n0 + n) * Dn + k0 + c] = tile[c][n];
    }
}

// =================== QKV GEMM, 8-phase-style 256x256 tile ===================
// (counted vmcnt(4), T2 slot-swizzle, T5 setprio)
// Epilogue: Q/K blocks write qkv[z][token][dim]; V blocks (z==2) write the
// TRANSPOSED vT[(b*1024+col)][s] directly as ushort4 — replaces k_tr_v.
__global__ __launch_bounds__(512, 2) void k_qkv8(const unsigned short* __restrict__ A,
                                                 const unsigned short* __restrict__ Bt,
                                                 const float* __restrict__ bq,
                                                 const float* __restrict__ bk,
                                                 const float* __restrict__ bv,
                                                 unsigned short* __restrict__ qkv,
                                                 unsigned short* __restrict__ vT) {
    extern __shared__ char smem[];  // 131072 bytes
    constexpr int K = 1024, NT = K / 64;  // 16 K-steps

    const int t = threadIdx.x;
    const int w = t >> 6, l = t & 63;
    const int wm = w >> 2, wn = w & 3;
    const int m0 = blockIdx.x * 256;
    const int n0 = blockIdx.y * 256;
    const int z = n0 >> 10;

    const float* bias = (z == 0) ? bq : (z == 1 ? bk : bv);
    float biasv[4];
#pragma unroll
    for (int nf = 0; nf < 4; ++nf)
        biasv[nf] = bias[(n0 + wn * 64 + nf * 16 + (l & 15)) & 1023];

    int aoff[2], boff[2], ldsoff[2];
#pragma unroll
    for (int i = 0; i < 2; ++i) {
        const int idx = i * 512 + t;
        const int row = idx >> 2;
        const int s = ((idx & 3) - row - (row >> 2)) & 3;
        aoff[i] = (m0 + row) * K + s * 8;
        boff[i] = (n0 + row) * K + s * 8;
        ldsoff[i] = idx * 16;
    }

    f32x4 acc[8][4] = {};

#pragma unroll
    for (int kh = 0; kh < 2; ++kh) {
        if (kh == 0) {
#pragma unroll
            for (int i = 0; i < 2; ++i) gll16(A + aoff[i], smem + ldsoff[i]);
#pragma unroll
            for (int i = 0; i < 2; ++i) gll16(Bt + boff[i], smem + 65536 + ldsoff[i]);
        } else {
#pragma unroll
            for (int i = 0; i < 2; ++i) gll16(A + aoff[i] + 32, smem + 16384 + ldsoff[i]);
#pragma unroll
            for (int i = 0; i < 2; ++i) gll16(Bt + boff[i] + 32, smem + 65536 + 16384 + ldsoff[i]);
        }
    }

    for (int kb = 0; kb < NT; ++kb) {
        const int c = kb & 1;
        const int kn = (kb + 1 < NT) ? kb + 1 : NT - 1;
        const int cn = c ^ 1;
        const int Abase = c * 32768;
        const int Bbase = 65536 + c * 32768;
        const int AbaseN = cn * 32768;
        const int BbaseN = 65536 + cn * 32768;

        bf16x8 bf[4], af[4];

#pragma unroll
        for (int ph = 0; ph < 4; ++ph) {
            const int kk = ph >> 1;
            const int mb = (ph & 1) * 4;

            if ((ph & 1) == 0) {
                asm volatile("s_waitcnt vmcnt(4)" ::: "memory");
            }
            __builtin_amdgcn_s_barrier();
            __builtin_amdgcn_sched_barrier(0);

            if ((ph & 1) == 0) {
#pragma unroll
                for (int nf = 0; nf < 4; ++nf) {
                    const int row = wn * 64 + nf * 16 + (l & 15);
                    const int byte = Bbase + kk * 16384 + row * 64 +
                                     ((((l >> 4) + row + (row >> 2)) & 3) * 16);
                    bf[nf] = *reinterpret_cast<const bf16x8*>(smem + byte);
                }
            }
#pragma unroll
            for (int mfl = 0; mfl < 4; ++mfl) {
                const int row = wm * 128 + (mb + mfl) * 16 + (l & 15);
                const int byte = Abase + kk * 16384 + row * 64 +
                                 ((((l >> 4) + row + (row >> 2)) & 3) * 16);
                af[mfl] = *reinterpret_cast<const bf16x8*>(smem + byte);
            }

            {
                const int khs = ph >> 1;
                if ((ph & 1) == 0) {
#pragma unroll
                    for (int i = 0; i < 2; ++i)
                        gll16(A + aoff[i] + kn * 64 + khs * 32,
                              smem + AbaseN + khs * 16384 + ldsoff[i]);
                } else {
#pragma unroll
                    for (int i = 0; i < 2; ++i)
                        gll16(Bt + boff[i] + kn * 64 + khs * 32,
                              smem + BbaseN + khs * 16384 + ldsoff[i]);
                }
            }

            asm volatile("s_waitcnt lgkmcnt(0)" ::: "memory");
            __builtin_amdgcn_sched_barrier(0);
            __builtin_amdgcn_s_setprio(1);
#pragma unroll
            for (int mfl = 0; mfl < 4; ++mfl)
#pragma unroll
                for (int nf = 0; nf < 4; ++nf)
                    acc[mb + mfl][nf] = __builtin_amdgcn_mfma_f32_16x16x32_bf16(
                        af[mfl], bf[nf], acc[mb + mfl][nf], 0, 0, 0);
            __builtin_amdgcn_s_setprio(0);
        }
    }

    asm volatile("s_waitcnt vmcnt(0)" ::: "memory");

    if (z < 2) {
        unsigned short* outz = qkv + (size_t)z * NTOKn * Dn;
#pragma unroll
        for (int mf = 0; mf < 8; ++mf) {
            const int row = m0 + wm * 128 + mf * 16 + (l >> 4) * 4;
#pragma unroll
            for (int nf = 0; nf < 4; ++nf) {
                const int col = (n0 + wn * 64 + nf * 16 + (l & 15)) & 1023;
#pragma unroll
                for (int i = 0; i < 4; ++i)
                    outz[(size_t)(row + i) * Dn + col] = f2bf(acc[mf][nf][i] + biasv[nf]);
            }
        }
    } else {
        // V: write transposed vT[(b*1024 + col)][s], 4 consecutive s per lane
#pragma unroll
        for (int mf = 0; mf < 8; ++mf) {
            const int row = m0 + wm * 128 + mf * 16 + (l >> 4) * 4;
            const int b = row >> 11, s = row & 2047;
#pragma unroll
            for (int nf = 0; nf < 4; ++nf) {
                const int col = (n0 + wn * 64 + nf * 16 + (l & 15)) & 1023;
                ushort4 o;
                o.x = f2bf(acc[mf][nf][0] + biasv[nf]);
                o.y = f2bf(acc[mf][nf][1] + biasv[nf]);
                o.z = f2bf(acc[mf][nf][2] + biasv[nf]);
                o.w = f2bf(acc[mf][nf][3] + biasv[nf]);
                *reinterpret_cast<ushort4*>(vT + ((size_t)(b * 1024 + col)) * Sn + s) = o;
            }
        }
    }
}

// =================== out-projection, 8-phase 256x256 tile, f32 out ===================
// out[4096][1024] = ctx[4096][1024] * wTo[1024][1024]^T + bo. Grid (16,4).
__global__ __launch_bounds__(512, 2) void k_op8(const unsigned short* __restrict__ A,
                                                const unsigned short* __restrict__ Bt,
                                                const float* __restrict__ bias,
                                                float* __restrict__ C) {
    extern __shared__ char smem[];  // 131072 bytes
    constexpr int K = 1024, NT = K / 64, N = 1024;

    const int t = threadIdx.x;
    const int w = t >> 6, l = t & 63;
    const int wm = w >> 2, wn = w & 3;
    const int m0 = blockIdx.x * 256;
    const int n0 = blockIdx.y * 256;

    float biasv[4];
#pragma unroll
    for (int nf = 0; nf < 4; ++nf)
        biasv[nf] = bias[n0 + wn * 64 + nf * 16 + (l & 15)];

    int aoff[2], boff[2], ldsoff[2];
#pragma unroll
    for (int i = 0; i < 2; ++i) {
        const int idx = i * 512 + t;
        const int row = idx >> 2;
        const int s = ((idx & 3) - row - (row >> 2)) & 3;
        aoff[i] = (m0 + row) * K + s * 8;
        boff[i] = (n0 + row) * K + s * 8;
        ldsoff[i] = idx * 16;
    }

    f32x4 acc[8][4] = {};

#pragma unroll
    for (int kh = 0; kh < 2; ++kh) {
        if (kh == 0) {
#pragma unroll
            for (int i = 0; i < 2; ++i) gll16(A + aoff[i], smem + ldsoff[i]);
#pragma unroll
            for (int i = 0; i < 2; ++i) gll16(Bt + boff[i], smem + 65536 + ldsoff[i]);
        } else {
#pragma unroll
            for (int i = 0; i < 2; ++i) gll16(A + aoff[i] + 32, smem + 16384 + ldsoff[i]);
#pragma unroll
            for (int i = 0; i < 2; ++i) gll16(Bt + boff[i] + 32, smem + 65536 + 16384 + ldsoff[i]);
        }
    }

    for (int kb = 0; kb < NT; ++kb) {
        const int c = kb & 1;
        const int kn = (kb + 1 < NT) ? kb + 1 : NT - 1;
        const int cn = c ^ 1;
        const int Abase = c * 32768;
        const int Bbase = 65536 + c * 32768;
        const int AbaseN = cn * 32768;
        const int BbaseN = 65536 + cn * 32768;

        bf16x8 bf[4], af[4];

#pragma unroll
        for (int ph = 0; ph < 4; ++ph) {
            const int kk = ph >> 1;
            const int mb = (ph & 1) * 4;

            if ((ph & 1) == 0) {
                asm volatile("s_waitcnt vmcnt(4)" ::: "memory");
            }
            __builtin_amdgcn_s_barrier();
            __builtin_amdgcn_sched_barrier(0);

            if ((ph & 1) == 0) {
#pragma unroll
                for (int nf = 0; nf < 4; ++nf) {
                    const int row = wn * 64 + nf * 16 + (l & 15);
                    const int byte = Bbase + kk * 16384 + row * 64 +
                                     ((((l >> 4) + row + (row >> 2)) & 3) * 16);
                    bf[nf] = *reinterpret_cast<const bf16x8*>(smem + byte);
                }
            }
#pragma unroll
            for (int mfl = 0; mfl < 4; ++mfl) {
                const int row = wm * 128 + (mb + mfl) * 16 + (l & 15);
                const int byte = Abase + kk * 16384 + row * 64 +
                                 ((((l >> 4) + row + (row >> 2)) & 3) * 16);
                af[mfl] = *reinterpret_cast<const bf16x8*>(smem + byte);
            }

            {
                const int khs = ph >> 1;
                if ((ph & 1) == 0) {
#pragma unroll
                    for (int i = 0; i < 2; ++i)
                        gll16(A + aoff[i] + kn * 64 + khs * 32,
                              smem + AbaseN + khs * 16384 + ldsoff[i]);
                } else {
#pragma unroll
                    for (int i = 0; i < 2; ++i)
                        gll16(Bt + boff[i] + kn * 64 + khs * 32,
                              smem + BbaseN + khs * 16384 + ldsoff[i]);
                }
            }

            asm volatile("s_waitcnt lgkmcnt(0)" ::: "memory");
            __builtin_amdgcn_sched_barrier(0);
            __builtin_amdgcn_s_setprio(1);
#pragma unroll
            for (int mfl = 0; mfl < 4; ++mfl)
#pragma unroll
                for (int nf = 0; nf < 4; ++nf)
                    acc[mb + mfl][nf] = __builtin_amdgcn_mfma_f32_16x16x32_bf16(
                        af[mfl], bf[nf], acc[mb + mfl][nf], 0, 0, 0);
            __builtin_amdgcn_s_setprio(0);
        }
    }

    asm volatile("s_waitcnt vmcnt(0)" ::: "memory");

#pragma unroll
    for (int mf = 0; mf < 8; ++mf) {
        const int row = m0 + wm * 128 + mf * 16 + (l >> 4) * 4;
#pragma unroll
        for (int nf = 0; nf < 4; ++nf) {
            const int col = n0 + wn * 64 + nf * 16 + (l & 15);
#pragma unroll
            for (int i = 0; i < 4; ++i)
                C[(size_t)(row + i) * N + col] = acc[mf][nf][i] + biasv[nf];
        }
    }
}

// ---------------- fused attention: attn = relu(QK^T*scale), ctx = attn @ V ----------------
// XCD-aware remap (each XCD owns 4 heads, K/V L2-resident); plain cached attn
// stores; store-overlap schedule with counted vmcnt(63).
__global__ __launch_bounds__(256, 2) void k_attn(const unsigned short* __restrict__ Qb,
                                                 const unsigned short* __restrict__ Kb,
                                                 const unsigned short* __restrict__ VTb,
                                                 float* __restrict__ attn,
                                                 unsigned short* __restrict__ ctx) {
    __shared__ unsigned short Ks[128 * 64];
    __shared__ unsigned short Vs[64 * 128];
    __shared__ unsigned short Ps[4][32][136];

    const int t = threadIdx.x;
    const int w = t >> 6, l = t & 63;

    // XCD-aware bijective remap (dispatch round-robins linear%8 across XCDs)
    const int lin = blockIdx.x + 16 * blockIdx.y;
    const int xcd = lin & 7, idx = lin >> 3;
    const int bh = xcd * 4 + (idx >> 4);
    const int q0 = (idx & 15) * 128;
    const int b = bh >> 4, h = bh & 15;
    const float scale = 0.125f;  // 1/sqrt(64)

    bf16x8 qf[2][2];
#pragma unroll
    for (int mi = 0; mi < 2; ++mi)
#pragma unroll
        for (int kk = 0; kk < 2; ++kk)
            qf[mi][kk] = *reinterpret_cast<const bf16x8*>(
                Qb + (size_t)(b * Sn + q0 + w * 32 + mi * 16 + (l & 15)) * Dn + h * DEP +
                kk * 32 + (l >> 4) * 8);

    const int krow = t >> 3;
    const int kcolswz = ((t & 7) * 8) ^ ((krow & 7) << 3);
    const int vrow = t >> 4;
    const int vcolswz = ((t & 15) * 8) ^ ((vrow & 7) << 3);
    unsigned short* lK = Ks + t * 8;
    unsigned short* lV = Vs + t * 8;

    f32x4 ctxa[2][4] = {};
    f32x4 sa[2][8];

    float* const abase = attn + (size_t)bh * Sn * Sn + (size_t)(q0 + w * 32) * Sn;

    auto STAGE = [&](int kb) {
#pragma unroll
        for (int is = 0; is < 4; ++is) {
            gll16(Kb + (size_t)(b * Sn + kb * 128 + is * 32 + krow) * Dn + h * DEP + kcolswz,
                  lK + is * 2048);
            gll16(VTb + (size_t)(bh * DEP + is * 16 + vrow) * Sn + kb * 128 + vcolswz,
                  lV + is * 2048);
        }
    };

    auto QKT = [&]() {
#pragma unroll
        for (int mi = 0; mi < 2; ++mi)
#pragma unroll
            for (int nj = 0; nj < 8; ++nj)
                sa[mi][nj] = (f32x4){0.f, 0.f, 0.f, 0.f};
#pragma unroll
        for (int nj = 0; nj < 8; ++nj) {
            const int kr = nj * 16 + (l & 15);
#pragma unroll
            for (int kk = 0; kk < 2; ++kk) {
                const int kidx = (kr * 64 + kk * 32 + (l >> 4) * 8) ^ ((kr & 7) << 3);
                const bf16x8 bfr = *reinterpret_cast<const bf16x8*>(Ks + kidx);
                sa[0][nj] = __builtin_amdgcn_mfma_f32_16x16x32_bf16(qf[0][kk], bfr, sa[0][nj], 0, 0, 0);
                sa[1][nj] = __builtin_amdgcn_mfma_f32_16x16x32_bf16(qf[1][kk], bfr, sa[1][nj], 0, 0, 0);
            }
        }
#pragma unroll
        for (int mi = 0; mi < 2; ++mi) {
#pragma unroll
            for (int nj = 0; nj < 8; ++nj) {
                f32x4 v = sa[mi][nj];
#pragma unroll
                for (int i = 0; i < 4; ++i) {
                    float p = v[i] * scale;
                    v[i] = p > 0.f ? p : 0.f;
                }
                sa[mi][nj] = v;
                const int kc = nj * 16 + (l & 15);
#pragma unroll
                for (int i = 0; i < 4; ++i)
                    Ps[w][mi * 16 + (l >> 4) * 4 + i][kc] = f2bf(v[i]);
            }
        }
    };

    auto PV = [&]() {
        bf16x8 pf[2][4];
#pragma unroll
        for (int mi = 0; mi < 2; ++mi)
#pragma unroll
            for (int kk = 0; kk < 4; ++kk)
                pf[mi][kk] = *reinterpret_cast<const bf16x8*>(
                    &Ps[w][mi * 16 + (l & 15)][kk * 32 + (l >> 4) * 8]);
#pragma unroll
        for (int nd = 0; nd < 4; ++nd) {
            const int vr = nd * 16 + (l & 15);
#pragma unroll
            for (int kk = 0; kk < 4; ++kk) {
                const int vidx = (vr * 128 + kk * 32 + (l >> 4) * 8) ^ ((vr & 7) << 3);
                const bf16x8 vfr = *reinterpret_cast<const bf16x8*>(Vs + vidx);
                ctxa[0][nd] = __builtin_amdgcn_mfma_f32_16x16x32_bf16(pf[0][kk], vfr, ctxa[0][nd], 0, 0, 0);
                ctxa[1][nd] = __builtin_amdgcn_mfma_f32_16x16x32_bf16(pf[1][kk], vfr, ctxa[1][nd], 0, 0, 0);
            }
        }
    };

    auto STORE_SA = [&](int kb) {  // plain cached stores
        float* arow = abase + kb * 128;
#pragma unroll
        for (int mi = 0; mi < 2; ++mi)
#pragma unroll
            for (int nj = 0; nj < 8; ++nj) {
                const int kc = nj * 16 + (l & 15);
#pragma unroll
                for (int i = 0; i < 4; ++i)
                    arow[(size_t)(mi * 16 + (l >> 4) * 4 + i) * Sn + kc] = sa[mi][nj][i];
            }
    };

    STAGE(0);
    asm volatile("s_waitcnt vmcnt(0)" ::: "memory");
    __builtin_amdgcn_s_barrier();
    __builtin_amdgcn_sched_barrier(0);
    QKT();
    PV();

    for (int kb = 1; kb < Sn / 128; ++kb) {
        asm volatile("s_waitcnt lgkmcnt(0)" ::: "memory");
        __builtin_amdgcn_s_barrier();
        __builtin_amdgcn_sched_barrier(0);
        STAGE(kb);
        asm volatile("" ::: "memory");
        STORE_SA(kb - 1);
        asm volatile("s_waitcnt vmcnt(63)" ::: "memory");
        __builtin_amdgcn_s_barrier();
        __builtin_amdgcn_sched_barrier(0);
        QKT();
        PV();
    }
    STORE_SA(Sn / 128 - 1);

#pragma unroll
    for (int mi = 0; mi < 2; ++mi) {
#pragma unroll
        for (int nd = 0; nd < 4; ++nd) {
            const int dc = nd * 16 + (l & 15);
#pragma unroll
            for (int i = 0; i < 4; ++i) {
                const int qr = q0 + w * 32 + mi * 16 + (l >> 4) * 4 + i;
                ctx[(size_t)(b * Sn + qr) * Dn + h * DEP + dc] = f2bf(ctxa[mi][nd][i]);
            }
        }
    }
}

extern "C" void kernel_launch(void* const* d_in, const int* in_sizes, int n_in,
                              void* d_out, int out_size, void* d_ws, size_t ws_size,
                              hipStream_t stream) {
    (void)in_sizes; (void)n_in; (void)out_size; (void)ws_size;
    const float* x  = (const float*)d_in[0];
    const float* wq = (const float*)d_in[1];
    const float* bq = (const float*)d_in[2];
    const float* wk = (const float*)d_in[3];
    const float* bk = (const float*)d_in[4];
    const float* wv = (const float*)d_in[5];
    const float* bv = (const float*)d_in[6];
    const float* wo = (const float*)d_in[7];
    const float* bo = (const float*)d_in[8];

    float* out  = (float*)d_out;
    float* attn = out + (size_t)Bn * Sn * Dn;  // outputs concatenated: (out, attn)

    char* ws = (char*)d_ws;
    unsigned short* xb = (unsigned short*)ws;  ws += (size_t)NTOKn * Dn * 2;       // 8 MB
    unsigned short* wT = (unsigned short*)ws;  ws += (size_t)4 * Dn * Dn * 2;      // 8 MB [q,k,v,o]
    unsigned short* qkv = (unsigned short*)ws; ws += (size_t)3 * NTOKn * Dn * 2;   // 24 MB (v third unused)
    unsigned short* vT = (unsigned short*)ws;  ws += (size_t)NTOKn * Dn * 2;       // 8 MB
    unsigned short* ctx = (unsigned short*)ws;                                     // 8 MB

    const size_t DD = (size_t)Dn * Dn;

    static bool attr_set = false;
    if (!attr_set) {
        hipFuncSetAttribute(reinterpret_cast<const void*>(k_qkv8),
                            hipFuncAttributeMaxDynamicSharedMemorySize, 131072);
        hipFuncSetAttribute(reinterpret_cast<const void*>(k_op8),
                            hipFuncAttributeMaxDynamicSharedMemorySize, 131072);
        attr_set = true;
    }

    k_prep<<<dim3(5120), 256, 0, stream>>>(x, wq, wk, wv, wo, xb,
                                           wT, wT + DD, wT + 2 * DD, wT + 3 * DD);
    k_qkv8<<<dim3(16, 12), 512, 131072, stream>>>(xb, wT, bq, bk, bv, qkv, vT);
    k_attn<<<dim3(16, 32), 256, 0, stream>>>(qkv, qkv + (size_t)NTOKn * Dn, vT, attn, ctx);
    k_op8<<<dim3(16, 4), 512, 131072, stream>>>(ctx, wT + 3 * DD, bo, out);
}

// Round 7
// 213.682 us; speedup vs baseline: 1.0902x; 1.0079x over previous
//
#include <hip/hip_runtime.h>
#include <hip/hip_bf16.h>

// Problem constants (reference: B=2, S=2048, D=1024, H=16, DEPTH=64)
constexpr int Bn = 2, Sn = 2048, Dn = 1024, Hn = 16, DEP = 64;
constexpr int NTOKn = Bn * Sn;  // 4096 rows for the token-dim GEMMs

typedef __bf16 bf16x8 __attribute__((ext_vector_type(8)));
typedef float f32x4 __attribute__((ext_vector_type(4)));

__device__ __forceinline__ unsigned short f2bf(float f) {
    union { __hip_bfloat16 h; unsigned short u; } cv;
    cv.h = __float2bfloat16(f);
    return cv.u;
}

// async global->LDS, 16B per lane. LDS dest must be wave-uniform base + lane*16.
__device__ __forceinline__ void gll16(const void* g, void* l) {
    __builtin_amdgcn_global_load_lds(
        (const __attribute__((address_space(1))) unsigned int*)g,
        (__attribute__((address_space(3))) unsigned int*)l, 16, 0, 0);
}

// ---------------- fused prep: x f32->bf16 convert + 4x weight transpose ----------------
__global__ __launch_bounds__(256) void k_prep(const float* __restrict__ x,
                                              const float* __restrict__ w0,
                                              const float* __restrict__ w1,
                                              const float* __restrict__ w2,
                                              const float* __restrict__ w3,
                                              unsigned short* __restrict__ xb,
                                              unsigned short* __restrict__ t0,
                                              unsigned short* __restrict__ t1,
                                              unsigned short* __restrict__ t2,
                                              unsigned short* __restrict__ t3) {
    const int bid = blockIdx.x;
    const int t = threadIdx.x;
    if (bid < 4096) {
        const int idx = (bid * 256 + t) * 4;
        float4 v = *reinterpret_cast<const float4*>(x + idx);
        ushort4 o;
        o.x = f2bf(v.x); o.y = f2bf(v.y); o.z = f2bf(v.z); o.w = f2bf(v.w);
        *reinterpret_cast<ushort4*>(xb + idx) = o;
        return;
    }
    const int b2 = bid - 4096;
    const float* w; unsigned short* tp;
    switch (b2 >> 8) {
        case 0: w = w0; tp = t0; break;
        case 1: w = w1; tp = t1; break;
        case 2: w = w2; tp = t2; break;
        default: w = w3; tp = t3; break;
    }
    __shared__ unsigned short tile[64][65];
    const int k0 = ((b2 & 255) >> 4) * 64, n0 = (b2 & 15) * 64;
    const int c = t & 63, rb = t >> 6;
#pragma unroll
    for (int i = 0; i < 16; ++i) {
        int r = rb + i * 4;
        tile[r][c] = f2bf(w[(size_t)(k0 + r) * Dn + n0 + c]);
    }
    __syncthreads();
#pragma unroll
    for (int i = 0; i < 16; ++i) {
        int n = rb + i * 4;
        tp[(size_t)(n0 + n) * Dn + k0 + c] = tile[c][n];
    }
}

// =================== QKV GEMM, 8-phase-style 256x256 tile ===================
// (counted vmcnt(4), T2 slot-swizzle, T5 setprio)
// Epilogue: Q/K blocks write qkv[z][token][dim]; V blocks (z==2) write the
// TRANSPOSED vT[(b*1024+col)][s] directly as ushort4 — replaces k_tr_v.
__global__ __launch_bounds__(512, 2) void k_qkv8(const unsigned short* __restrict__ A,
                                                 const unsigned short* __restrict__ Bt,
                                                 const float* __restrict__ bq,
                                                 const float* __restrict__ bk,
                                                 const float* __restrict__ bv,
                                                 unsigned short* __restrict__ qkv,
                                                 unsigned short* __restrict__ vT) {
    extern __shared__ char smem[];  // 131072 bytes
    constexpr int K = 1024, NT = K / 64;  // 16 K-steps

    const int t = threadIdx.x;
    const int w = t >> 6, l = t & 63;
    const int wm = w >> 2, wn = w & 3;
    const int m0 = blockIdx.x * 256;
    const int n0 = blockIdx.y * 256;
    const int z = n0 >> 10;

    const float* bias = (z == 0) ? bq : (z == 1 ? bk : bv);
    float biasv[4];
#pragma unroll
    for (int nf = 0; nf < 4; ++nf)
        biasv[nf] = bias[(n0 + wn * 64 + nf * 16 + (l & 15)) & 1023];

    int aoff[2], boff[2], ldsoff[2];
#pragma unroll
    for (int i = 0; i < 2; ++i) {
        const int idx = i * 512 + t;
        const int row = idx >> 2;
        const int s = ((idx & 3) - row - (row >> 2)) & 3;
        aoff[i] = (m0 + row) * K + s * 8;
        boff[i] = (n0 + row) * K + s * 8;
        ldsoff[i] = idx * 16;
    }

    f32x4 acc[8][4] = {};

#pragma unroll
    for (int kh = 0; kh < 2; ++kh) {
        if (kh == 0) {
#pragma unroll
            for (int i = 0; i < 2; ++i) gll16(A + aoff[i], smem + ldsoff[i]);
#pragma unroll
            for (int i = 0; i < 2; ++i) gll16(Bt + boff[i], smem + 65536 + ldsoff[i]);
        } else {
#pragma unroll
            for (int i = 0; i < 2; ++i) gll16(A + aoff[i] + 32, smem + 16384 + ldsoff[i]);
#pragma unroll
            for (int i = 0; i < 2; ++i) gll16(Bt + boff[i] + 32, smem + 65536 + 16384 + ldsoff[i]);
        }
    }

    for (int kb = 0; kb < NT; ++kb) {
        const int c = kb & 1;
        const int kn = (kb + 1 < NT) ? kb + 1 : NT - 1;
        const int cn = c ^ 1;
        const int Abase = c * 32768;
        const int Bbase = 65536 + c * 32768;
        const int AbaseN = cn * 32768;
        const int BbaseN = 65536 + cn * 32768;

        bf16x8 bf[4], af[4];

#pragma unroll
        for (int ph = 0; ph < 4; ++ph) {
            const int kk = ph >> 1;
            const int mb = (ph & 1) * 4;

            if ((ph & 1) == 0) {
                asm volatile("s_waitcnt vmcnt(4)" ::: "memory");
            }
            __builtin_amdgcn_s_barrier();
            __builtin_amdgcn_sched_barrier(0);

            if ((ph & 1) == 0) {
#pragma unroll
                for (int nf = 0; nf < 4; ++nf) {
                    const int row = wn * 64 + nf * 16 + (l & 15);
                    const int byte = Bbase + kk * 16384 + row * 64 +
                                     ((((l >> 4) + row + (row >> 2)) & 3) * 16);
                    bf[nf] = *reinterpret_cast<const bf16x8*>(smem + byte);
                }
            }
#pragma unroll
            for (int mfl = 0; mfl < 4; ++mfl) {
                const int row = wm * 128 + (mb + mfl) * 16 + (l & 15);
                const int byte = Abase + kk * 16384 + row * 64 +
                                 ((((l >> 4) + row + (row >> 2)) & 3) * 16);
                af[mfl] = *reinterpret_cast<const bf16x8*>(smem + byte);
            }

            {
                const int khs = ph >> 1;
                if ((ph & 1) == 0) {
#pragma unroll
                    for (int i = 0; i < 2; ++i)
                        gll16(A + aoff[i] + kn * 64 + khs * 32,
                              smem + AbaseN + khs * 16384 + ldsoff[i]);
                } else {
#pragma unroll
                    for (int i = 0; i < 2; ++i)
                        gll16(Bt + boff[i] + kn * 64 + khs * 32,
                              smem + BbaseN + khs * 16384 + ldsoff[i]);
                }
            }

            asm volatile("s_waitcnt lgkmcnt(0)" ::: "memory");
            __builtin_amdgcn_sched_barrier(0);
            __builtin_amdgcn_s_setprio(1);
#pragma unroll
            for (int mfl = 0; mfl < 4; ++mfl)
#pragma unroll
                for (int nf = 0; nf < 4; ++nf)
                    acc[mb + mfl][nf] = __builtin_amdgcn_mfma_f32_16x16x32_bf16(
                        af[mfl], bf[nf], acc[mb + mfl][nf], 0, 0, 0);
            __builtin_amdgcn_s_setprio(0);
        }
    }

    asm volatile("s_waitcnt vmcnt(0)" ::: "memory");

    if (z < 2) {
        unsigned short* outz = qkv + (size_t)z * NTOKn * Dn;
#pragma unroll
        for (int mf = 0; mf < 8; ++mf) {
            const int row = m0 + wm * 128 + mf * 16 + (l >> 4) * 4;
#pragma unroll
            for (int nf = 0; nf < 4; ++nf) {
                const int col = (n0 + wn * 64 + nf * 16 + (l & 15)) & 1023;
#pragma unroll
                for (int i = 0; i < 4; ++i)
                    outz[(size_t)(row + i) * Dn + col] = f2bf(acc[mf][nf][i] + biasv[nf]);
            }
        }
    } else {
        // V: write transposed vT[(b*1024 + col)][s], 4 consecutive s per lane
#pragma unroll
        for (int mf = 0; mf < 8; ++mf) {
            const int row = m0 + wm * 128 + mf * 16 + (l >> 4) * 4;
            const int b = row >> 11, s = row & 2047;
#pragma unroll
            for (int nf = 0; nf < 4; ++nf) {
                const int col = (n0 + wn * 64 + nf * 16 + (l & 15)) & 1023;
                ushort4 o;
                o.x = f2bf(acc[mf][nf][0] + biasv[nf]);
                o.y = f2bf(acc[mf][nf][1] + biasv[nf]);
                o.z = f2bf(acc[mf][nf][2] + biasv[nf]);
                o.w = f2bf(acc[mf][nf][3] + biasv[nf]);
                *reinterpret_cast<ushort4*>(vT + ((size_t)(b * 1024 + col)) * Sn + s) = o;
            }
        }
    }
}

// ---------------- bf16 GEMM (m97 structure, 128x128) for the out-projection ----------------
// 256 blocks -> full-chip spread; better than 256^2 8-phase here (R6 lesson:
// 64-block grid starves 192 CUs).
__global__ __launch_bounds__(256) void k_gemm_op(const unsigned short* __restrict__ A,
                                                 const unsigned short* __restrict__ Bt,
                                                 const float* __restrict__ bias,
                                                 float* __restrict__ C,
                                                 int M, int N, int K) {
    __shared__ unsigned short As[128][32];
    __shared__ unsigned short Bs[128][32];
    const int t = threadIdx.x;
    const int w = t >> 6, l = t & 63;
    const int m0 = blockIdx.x * 128, n0 = blockIdx.y * 128;
    const int wr = (w >> 1) * 64, wc = (w & 1) * 64;

    const int lrow = t >> 2;
    const int lcol = (t & 3) * 8;
    const unsigned short* gA = A + (size_t)(m0 + lrow) * K + lcol;
    const unsigned short* gB = Bt + (size_t)(n0 + lrow) * K + lcol;
    unsigned short* lA = &As[0][0] + t * 8;
    unsigned short* lB = &Bs[0][0] + t * 8;

    f32x4 acc[4][4] = {};

    for (int k0 = 0; k0 < K; k0 += 32) {
        __syncthreads();
        gll16(gA + k0, lA);
        gll16(gA + (size_t)64 * K + k0, lA + 2048);
        gll16(gB + k0, lB);
        gll16(gB + (size_t)64 * K + k0, lB + 2048);
        __syncthreads();

        bf16x8 af[4], bfv[4];
#pragma unroll
        for (int i = 0; i < 4; ++i)
            af[i] = *reinterpret_cast<const bf16x8*>(&As[wr + i * 16 + (l & 15)][(l >> 4) * 8]);
#pragma unroll
        for (int i = 0; i < 4; ++i)
            bfv[i] = *reinterpret_cast<const bf16x8*>(&Bs[wc + i * 16 + (l & 15)][(l >> 4) * 8]);
#pragma unroll
        for (int mi = 0; mi < 4; ++mi)
#pragma unroll
            for (int ni = 0; ni < 4; ++ni)
                acc[mi][ni] =
                    __builtin_amdgcn_mfma_f32_16x16x32_bf16(af[mi], bfv[ni], acc[mi][ni], 0, 0, 0);
    }

#pragma unroll
    for (int mi = 0; mi < 4; ++mi) {
        const int row = m0 + wr + mi * 16 + (l >> 4) * 4;
#pragma unroll
        for (int ni = 0; ni < 4; ++ni) {
            const int col = n0 + wc + ni * 16 + (l & 15);
            const float bv = bias[col];
#pragma unroll
            for (int i = 0; i < 4; ++i)
                C[(size_t)(row + i) * N + col] = acc[mi][ni][i] + bv;
        }
    }
}

// ---------------- fused attention: attn = relu(QK^T*scale), ctx = attn @ V ----------------
// XCD-aware remap (each XCD owns 4 heads, K/V L2-resident); plain cached attn
// stores; store-overlap schedule with counted vmcnt(63).
__global__ __launch_bounds__(256, 2) void k_attn(const unsigned short* __restrict__ Qb,
                                                 const unsigned short* __restrict__ Kb,
                                                 const unsigned short* __restrict__ VTb,
                                                 float* __restrict__ attn,
                                                 unsigned short* __restrict__ ctx) {
    __shared__ unsigned short Ks[128 * 64];
    __shared__ unsigned short Vs[64 * 128];
    __shared__ unsigned short Ps[4][32][136];

    const int t = threadIdx.x;
    const int w = t >> 6, l = t & 63;

    // XCD-aware bijective remap (dispatch round-robins linear%8 across XCDs)
    const int lin = blockIdx.x + 16 * blockIdx.y;
    const int xcd = lin & 7, idx = lin >> 3;
    const int bh = xcd * 4 + (idx >> 4);
    const int q0 = (idx & 15) * 128;
    const int b = bh >> 4, h = bh & 15;
    const float scale = 0.125f;  // 1/sqrt(64)

    bf16x8 qf[2][2];
#pragma unroll
    for (int mi = 0; mi < 2; ++mi)
#pragma unroll
        for (int kk = 0; kk < 2; ++kk)
            qf[mi][kk] = *reinterpret_cast<const bf16x8*>(
                Qb + (size_t)(b * Sn + q0 + w * 32 + mi * 16 + (l & 15)) * Dn + h * DEP +
                kk * 32 + (l >> 4) * 8);

    const int krow = t >> 3;
    const int kcolswz = ((t & 7) * 8) ^ ((krow & 7) << 3);
    const int vrow = t >> 4;
    const int vcolswz = ((t & 15) * 8) ^ ((vrow & 7) << 3);
    unsigned short* lK = Ks + t * 8;
    unsigned short* lV = Vs + t * 8;

    f32x4 ctxa[2][4] = {};
    f32x4 sa[2][8];

    float* const abase = attn + (size_t)bh * Sn * Sn + (size_t)(q0 + w * 32) * Sn;

    auto STAGE = [&](int kb) {
#pragma unroll
        for (int is = 0; is < 4; ++is) {
            gll16(Kb + (size_t)(b * Sn + kb * 128 + is * 32 + krow) * Dn + h * DEP + kcolswz,
                  lK + is * 2048);
            gll16(VTb + (size_t)(bh * DEP + is * 16 + vrow) * Sn + kb * 128 + vcolswz,
                  lV + is * 2048);
        }
    };

    auto QKT = [&]() {
#pragma unroll
        for (int mi = 0; mi < 2; ++mi)
#pragma unroll
            for (int nj = 0; nj < 8; ++nj)
                sa[mi][nj] = (f32x4){0.f, 0.f, 0.f, 0.f};
#pragma unroll
        for (int nj = 0; nj < 8; ++nj) {
            const int kr = nj * 16 + (l & 15);
#pragma unroll
            for (int kk = 0; kk < 2; ++kk) {
                const int kidx = (kr * 64 + kk * 32 + (l >> 4) * 8) ^ ((kr & 7) << 3);
                const bf16x8 bfr = *reinterpret_cast<const bf16x8*>(Ks + kidx);
                sa[0][nj] = __builtin_amdgcn_mfma_f32_16x16x32_bf16(qf[0][kk], bfr, sa[0][nj], 0, 0, 0);
                sa[1][nj] = __builtin_amdgcn_mfma_f32_16x16x32_bf16(qf[1][kk], bfr, sa[1][nj], 0, 0, 0);
            }
        }
#pragma unroll
        for (int mi = 0; mi < 2; ++mi) {
#pragma unroll
            for (int nj = 0; nj < 8; ++nj) {
                f32x4 v = sa[mi][nj];
#pragma unroll
                for (int i = 0; i < 4; ++i) {
                    float p = v[i] * scale;
                    v[i] = p > 0.f ? p : 0.f;
                }
                sa[mi][nj] = v;
                const int kc = nj * 16 + (l & 15);
#pragma unroll
                for (int i = 0; i < 4; ++i)
                    Ps[w][mi * 16 + (l >> 4) * 4 + i][kc] = f2bf(v[i]);
            }
        }
    };

    auto PV = [&]() {
        bf16x8 pf[2][4];
#pragma unroll
        for (int mi = 0; mi < 2; ++mi)
#pragma unroll
            for (int kk = 0; kk < 4; ++kk)
                pf[mi][kk] = *reinterpret_cast<const bf16x8*>(
                    &Ps[w][mi * 16 + (l & 15)][kk * 32 + (l >> 4) * 8]);
#pragma unroll
        for (int nd = 0; nd < 4; ++nd) {
            const int vr = nd * 16 + (l & 15);
#pragma unroll
            for (int kk = 0; kk < 4; ++kk) {
                const int vidx = (vr * 128 + kk * 32 + (l >> 4) * 8) ^ ((vr & 7) << 3);
                const bf16x8 vfr = *reinterpret_cast<const bf16x8*>(Vs + vidx);
                ctxa[0][nd] = __builtin_amdgcn_mfma_f32_16x16x32_bf16(pf[0][kk], vfr, ctxa[0][nd], 0, 0, 0);
                ctxa[1][nd] = __builtin_amdgcn_mfma_f32_16x16x32_bf16(pf[1][kk], vfr, ctxa[1][nd], 0, 0, 0);
            }
        }
    };

    auto STORE_SA = [&](int kb) {  // plain cached stores
        float* arow = abase + kb * 128;
#pragma unroll
        for (int mi = 0; mi < 2; ++mi)
#pragma unroll
            for (int nj = 0; nj < 8; ++nj) {
                const int kc = nj * 16 + (l & 15);
#pragma unroll
                for (int i = 0; i < 4; ++i)
                    arow[(size_t)(mi * 16 + (l >> 4) * 4 + i) * Sn + kc] = sa[mi][nj][i];
            }
    };

    STAGE(0);
    asm volatile("s_waitcnt vmcnt(0)" ::: "memory");
    __builtin_amdgcn_s_barrier();
    __builtin_amdgcn_sched_barrier(0);
    QKT();
    PV();

    for (int kb = 1; kb < Sn / 128; ++kb) {
        asm volatile("s_waitcnt lgkmcnt(0)" ::: "memory");
        __builtin_amdgcn_s_barrier();
        __builtin_amdgcn_sched_barrier(0);
        STAGE(kb);
        asm volatile("" ::: "memory");
        STORE_SA(kb - 1);
        asm volatile("s_waitcnt vmcnt(63)" ::: "memory");
        __builtin_amdgcn_s_barrier();
        __builtin_amdgcn_sched_barrier(0);
        QKT();
        PV();
    }
    STORE_SA(Sn / 128 - 1);

#pragma unroll
    for (int mi = 0; mi < 2; ++mi) {
#pragma unroll
        for (int nd = 0; nd < 4; ++nd) {
            const int dc = nd * 16 + (l & 15);
#pragma unroll
            for (int i = 0; i < 4; ++i) {
                const int qr = q0 + w * 32 + mi * 16 + (l >> 4) * 4 + i;
                ctx[(size_t)(b * Sn + qr) * Dn + h * DEP + dc] = f2bf(ctxa[mi][nd][i]);
            }
        }
    }
}

extern "C" void kernel_launch(void* const* d_in, const int* in_sizes, int n_in,
                              void* d_out, int out_size, void* d_ws, size_t ws_size,
                              hipStream_t stream) {
    (void)in_sizes; (void)n_in; (void)out_size; (void)ws_size;
    const float* x  = (const float*)d_in[0];
    const float* wq = (const float*)d_in[1];
    const float* bq = (const float*)d_in[2];
    const float* wk = (const float*)d_in[3];
    const float* bk = (const float*)d_in[4];
    const float* wv = (const float*)d_in[5];
    const float* bv = (const float*)d_in[6];
    const float* wo = (const float*)d_in[7];
    const float* bo = (const float*)d_in[8];

    float* out  = (float*)d_out;
    float* attn = out + (size_t)Bn * Sn * Dn;  // outputs concatenated: (out, attn)

    char* ws = (char*)d_ws;
    unsigned short* xb = (unsigned short*)ws;  ws += (size_t)NTOKn * Dn * 2;       // 8 MB
    unsigned short* wT = (unsigned short*)ws;  ws += (size_t)4 * Dn * Dn * 2;      // 8 MB [q,k,v,o]
    unsigned short* qkv = (unsigned short*)ws; ws += (size_t)3 * NTOKn * Dn * 2;   // 24 MB (v third unused)
    unsigned short* vT = (unsigned short*)ws;  ws += (size_t)NTOKn * Dn * 2;       // 8 MB
    unsigned short* ctx = (unsigned short*)ws;                                     // 8 MB

    const size_t DD = (size_t)Dn * Dn;

    static bool attr_set = false;
    if (!attr_set) {
        hipFuncSetAttribute(reinterpret_cast<const void*>(k_qkv8),
                            hipFuncAttributeMaxDynamicSharedMemorySize, 131072);
        attr_set = true;
    }

    k_prep<<<dim3(5120), 256, 0, stream>>>(x, wq, wk, wv, wo, xb,
                                           wT, wT + DD, wT + 2 * DD, wT + 3 * DD);
    k_qkv8<<<dim3(16, 12), 512, 131072, stream>>>(xb, wT, bq, bk, bv, qkv, vT);
    k_attn<<<dim3(16, 32), 256, 0, stream>>>(qkv, qkv + (size_t)NTOKn * Dn, vT, attn, ctx);
    k_gemm_op<<<dim3(32, 8), 256, 0, stream>>>(ctx, wT + 3 * DD, bo, out, NTOKn, Dn, Dn);
}